// Round 1
// baseline (6760.741 us; speedup 1.0000x reference)
//
#include <hip/hip_runtime.h>
#include <hip/hip_bf16.h>

#define N_NODES 100000
#define N_EDGES 1600000
#define D_IN    480
#define D_OUT   256
#define NEG_SLOPE 0.2f

// ---------- float <-> order-preserving u32 key (for atomicMax on float) ----
__device__ __forceinline__ unsigned f2key(float f) {
    unsigned b = __float_as_uint(f);
    return (b & 0x80000000u) ? ~b : (b | 0x80000000u);
}
__device__ __forceinline__ float key2f(unsigned k) {
    unsigned b = (k & 0x80000000u) ? (k & 0x7fffffffu) : ~k;
    return __uint_as_float(b);
}

// ---------------------------------------------------------------- GEMM ----
// y[n, 256] = x[n, 480] @ W[480, 256] + b ; blockIdx.z selects (W_l) vs (W_r)
#define BM 64
#define BN 64
#define BK 32

__global__ __launch_bounds__(256) void gemm_xw(
    const float* __restrict__ x,
    const float* __restrict__ Wl, const float* __restrict__ bl, float* __restrict__ yl,
    const float* __restrict__ Wr, const float* __restrict__ br, float* __restrict__ yr)
{
    const float* W = (blockIdx.z == 0) ? Wl : Wr;
    const float* bias = (blockIdx.z == 0) ? bl : br;
    float* y = (blockIdx.z == 0) ? yl : yr;

    __shared__ float As[BK][BM + 1];  // [k][row], +1 pad: transposed-store conflicts -> 2-way
    __shared__ float Bs[BK][BN];      // [k][col]

    const int r0 = blockIdx.x * BM;
    const int c0 = blockIdx.y * BN;
    const int t  = threadIdx.x;
    const int ty = t >> 4;    // 0..15 -> rows ty*4..+3
    const int tx = t & 15;    // 0..15 -> cols tx*4..+3

    float acc[4][4] = {};

    for (int k0 = 0; k0 < D_IN; k0 += BK) {
        // --- load A tile: rows r0..r0+63, k k0..k0+31 (transposed into LDS)
        {
            const int row = t >> 3;          // 0..31
            const int kk  = (t & 7) * 4;     // 0,4,...,28
            #pragma unroll
            for (int rr = row; rr < BM; rr += 32) {
                const int gr = r0 + rr;
                float4 v = make_float4(0.f, 0.f, 0.f, 0.f);
                if (gr < N_NODES)
                    v = *(const float4*)(x + (size_t)gr * D_IN + k0 + kk);
                As[kk + 0][rr] = v.x; As[kk + 1][rr] = v.y;
                As[kk + 2][rr] = v.z; As[kk + 3][rr] = v.w;
            }
        }
        // --- load B tile: k k0..k0+31, cols c0..c0+63
        {
            const int kk  = t >> 4;          // 0..15 (two rows per thread)
            const int col = (t & 15) * 4;
            *(float4*)&Bs[kk][col] =
                *(const float4*)(W + (size_t)(k0 + kk) * D_OUT + c0 + col);
            *(float4*)&Bs[kk + 16][col] =
                *(const float4*)(W + (size_t)(k0 + kk + 16) * D_OUT + c0 + col);
        }
        __syncthreads();

        #pragma unroll
        for (int kk = 0; kk < BK; ++kk) {
            float a0 = As[kk][ty * 4 + 0];
            float a1 = As[kk][ty * 4 + 1];
            float a2 = As[kk][ty * 4 + 2];
            float a3 = As[kk][ty * 4 + 3];
            float b0 = Bs[kk][tx * 4 + 0];
            float b1 = Bs[kk][tx * 4 + 1];
            float b2 = Bs[kk][tx * 4 + 2];
            float b3 = Bs[kk][tx * 4 + 3];
            acc[0][0] += a0 * b0; acc[0][1] += a0 * b1; acc[0][2] += a0 * b2; acc[0][3] += a0 * b3;
            acc[1][0] += a1 * b0; acc[1][1] += a1 * b1; acc[1][2] += a1 * b2; acc[1][3] += a1 * b3;
            acc[2][0] += a2 * b0; acc[2][1] += a2 * b1; acc[2][2] += a2 * b2; acc[2][3] += a2 * b3;
            acc[3][0] += a3 * b0; acc[3][1] += a3 * b1; acc[3][2] += a3 * b2; acc[3][3] += a3 * b3;
        }
        __syncthreads();
    }

    const int gc = c0 + tx * 4;
    const float4 bv = *(const float4*)(bias + gc);
    #pragma unroll
    for (int i = 0; i < 4; ++i) {
        const int gr = r0 + ty * 4 + i;
        if (gr < N_NODES) {
            float4 o;
            o.x = acc[i][0] + bv.x; o.y = acc[i][1] + bv.y;
            o.z = acc[i][2] + bv.z; o.w = acc[i][3] + bv.w;
            *(float4*)(y + (size_t)gr * D_OUT + gc) = o;
        }
    }
}

// ------------------------------------------------------------- init -------
// out <- bias broadcast; emax keys <- 0 (== -NaN key, below every real float);
// denom <- 0
__global__ void init_k(float* __restrict__ out, const float* __restrict__ bias,
                       unsigned* __restrict__ emax, float* __restrict__ denom)
{
    const int i = blockIdx.x * 256 + threadIdx.x;   // grid covers N_NODES*256
    out[i] = bias[i & (D_OUT - 1)];
    if (i < N_NODES) { emax[i] = 0u; denom[i] = 0.f; }
}

// -------------------------------------------------- edge pass 1: logits ---
// one 64-lane wave per edge; lane handles 4 of 256 dims
__global__ __launch_bounds__(256) void edge_logits(
    const float* __restrict__ xl, const float* __restrict__ xr,
    const int* __restrict__ ei, const float* __restrict__ att,
    float* __restrict__ e_buf, unsigned* __restrict__ emax)
{
    const int wave = (blockIdx.x * blockDim.x + threadIdx.x) >> 6;
    const int lane = threadIdx.x & 63;
    if (wave >= N_EDGES) return;
    const int src = ei[wave];
    const int dst = ei[N_EDGES + wave];

    const float4 a = *(const float4*)(att + lane * 4);
    const float4 l = *(const float4*)(xl + (size_t)src * D_OUT + lane * 4);
    const float4 r = *(const float4*)(xr + (size_t)dst * D_OUT + lane * 4);

    float h0 = l.x + r.x, h1 = l.y + r.y, h2 = l.z + r.z, h3 = l.w + r.w;
    h0 = h0 > 0.f ? h0 : NEG_SLOPE * h0;
    h1 = h1 > 0.f ? h1 : NEG_SLOPE * h1;
    h2 = h2 > 0.f ? h2 : NEG_SLOPE * h2;
    h3 = h3 > 0.f ? h3 : NEG_SLOPE * h3;
    float s = h0 * a.x + h1 * a.y + h2 * a.z + h3 * a.w;

    #pragma unroll
    for (int off = 32; off > 0; off >>= 1) s += __shfl_down(s, off, 64);

    if (lane == 0) {
        e_buf[wave] = s;
        atomicMax(&emax[dst], f2key(s));
    }
}

// --------------------------------------- edge pass 2: exp + denominator ---
__global__ void edge_soft(const float* __restrict__ e_buf, const int* __restrict__ ei,
                          const unsigned* __restrict__ emax,
                          float* __restrict__ ex_buf, float* __restrict__ denom)
{
    const int e = blockIdx.x * blockDim.x + threadIdx.x;
    if (e >= N_EDGES) return;
    const int dst = ei[N_EDGES + e];
    const float m = key2f(emax[dst]);
    const float v = expf(e_buf[e] - m);
    ex_buf[e] = v;
    atomicAdd(&denom[dst], v);
}

// ------------------------------------ edge pass 3: weighted scatter-sum ---
__global__ __launch_bounds__(256) void edge_accum(
    const float* __restrict__ xl, const int* __restrict__ ei,
    const float* __restrict__ ex_buf, const float* __restrict__ denom,
    float* __restrict__ out)
{
    const int wave = (blockIdx.x * blockDim.x + threadIdx.x) >> 6;
    const int lane = threadIdx.x & 63;
    if (wave >= N_EDGES) return;
    const int src = ei[wave];
    const int dst = ei[N_EDGES + wave];
    const float alpha = ex_buf[wave] / (denom[dst] + 1e-16f);

    const float4 l = *(const float4*)(xl + (size_t)src * D_OUT + lane * 4);
    float* o = out + (size_t)dst * D_OUT + lane * 4;
    atomicAdd(o + 0, alpha * l.x);
    atomicAdd(o + 1, alpha * l.y);
    atomicAdd(o + 2, alpha * l.z);
    atomicAdd(o + 3, alpha * l.w);
}

// --------------------------------------------------------------- launch ---
extern "C" void kernel_launch(void* const* d_in, const int* in_sizes, int n_in,
                              void* d_out, int out_size, void* d_ws, size_t ws_size,
                              hipStream_t stream)
{
    const float* x   = (const float*)d_in[0];
    const int*   ei  = (const int*)  d_in[1];
    const float* W_l = (const float*)d_in[2];
    const float* b_l = (const float*)d_in[3];
    const float* W_r = (const float*)d_in[4];
    const float* b_r = (const float*)d_in[5];
    const float* att = (const float*)d_in[6];
    const float* bias= (const float*)d_in[7];
    float* out = (float*)d_out;

    // workspace layout (fp32 elements)
    float*    xl     = (float*)d_ws;                       // N*256
    float*    xr     = xl + (size_t)N_NODES * D_OUT;       // N*256
    float*    e_buf  = xr + (size_t)N_NODES * D_OUT;       // E
    float*    ex_buf = e_buf + N_EDGES;                    // E
    unsigned* emax   = (unsigned*)(ex_buf + N_EDGES);      // N
    float*    denom  = (float*)(emax + N_NODES);           // N

    // 1) x_l / x_r dual GEMM
    dim3 ggrid((N_NODES + BM - 1) / BM, D_OUT / BN, 2);
    gemm_xw<<<ggrid, 256, 0, stream>>>(x, W_l, b_l, xl, W_r, b_r, xr);

    // 2) init out=bias, emax=-inf-key, denom=0
    init_k<<<(N_NODES * D_OUT) / 256, 256, 0, stream>>>(out, bias, emax, denom);

    // 3) logits + segment max
    edge_logits<<<N_EDGES / 4, 256, 0, stream>>>(xl, xr, ei, att, e_buf, emax);

    // 4) exp + segment sum
    edge_soft<<<(N_EDGES + 255) / 256, 256, 0, stream>>>(e_buf, ei, emax, ex_buf, denom);

    // 5) alpha-weighted scatter accumulate
    edge_accum<<<N_EDGES / 4, 256, 0, stream>>>(xl, ei, ex_buf, denom, out);
}

// Round 2
// 1870.219 us; speedup vs baseline: 3.6149x; 3.6149x over previous
//
#include <hip/hip_runtime.h>
#include <hip/hip_bf16.h>

#define N_NODES 100000
#define N_EDGES 1600000
#define D_IN    480
#define D_OUT   256
#define NEG_SLOPE 0.2f

// ---------------------------------------------------------------- GEMM ----
// y[n, 256] = x[n, 480] @ W[480, 256] + b ; blockIdx.z selects (W_l) vs (W_r)
#define BM 64
#define BN 64
#define BK 32

__global__ __launch_bounds__(256) void gemm_xw(
    const float* __restrict__ x,
    const float* __restrict__ Wl, const float* __restrict__ bl, float* __restrict__ yl,
    const float* __restrict__ Wr, const float* __restrict__ br, float* __restrict__ yr)
{
    const float* W = (blockIdx.z == 0) ? Wl : Wr;
    const float* bias = (blockIdx.z == 0) ? bl : br;
    float* y = (blockIdx.z == 0) ? yl : yr;

    __shared__ float As[BK][BM + 1];
    __shared__ float Bs[BK][BN];

    const int r0 = blockIdx.x * BM;
    const int c0 = blockIdx.y * BN;
    const int t  = threadIdx.x;
    const int ty = t >> 4;
    const int tx = t & 15;

    float acc[4][4] = {};

    for (int k0 = 0; k0 < D_IN; k0 += BK) {
        {
            const int row = t >> 3;
            const int kk  = (t & 7) * 4;
            #pragma unroll
            for (int rr = row; rr < BM; rr += 32) {
                const int gr = r0 + rr;
                float4 v = make_float4(0.f, 0.f, 0.f, 0.f);
                if (gr < N_NODES)
                    v = *(const float4*)(x + (size_t)gr * D_IN + k0 + kk);
                As[kk + 0][rr] = v.x; As[kk + 1][rr] = v.y;
                As[kk + 2][rr] = v.z; As[kk + 3][rr] = v.w;
            }
        }
        {
            const int kk  = t >> 4;
            const int col = (t & 15) * 4;
            *(float4*)&Bs[kk][col] =
                *(const float4*)(W + (size_t)(k0 + kk) * D_OUT + c0 + col);
            *(float4*)&Bs[kk + 16][col] =
                *(const float4*)(W + (size_t)(k0 + kk + 16) * D_OUT + c0 + col);
        }
        __syncthreads();

        #pragma unroll
        for (int kk = 0; kk < BK; ++kk) {
            float a0 = As[kk][ty * 4 + 0];
            float a1 = As[kk][ty * 4 + 1];
            float a2 = As[kk][ty * 4 + 2];
            float a3 = As[kk][ty * 4 + 3];
            float b0 = Bs[kk][tx * 4 + 0];
            float b1 = Bs[kk][tx * 4 + 1];
            float b2 = Bs[kk][tx * 4 + 2];
            float b3 = Bs[kk][tx * 4 + 3];
            acc[0][0] += a0 * b0; acc[0][1] += a0 * b1; acc[0][2] += a0 * b2; acc[0][3] += a0 * b3;
            acc[1][0] += a1 * b0; acc[1][1] += a1 * b1; acc[1][2] += a1 * b2; acc[1][3] += a1 * b3;
            acc[2][0] += a2 * b0; acc[2][1] += a2 * b1; acc[2][2] += a2 * b2; acc[2][3] += a2 * b3;
            acc[3][0] += a3 * b0; acc[3][1] += a3 * b1; acc[3][2] += a3 * b2; acc[3][3] += a3 * b3;
        }
        __syncthreads();
    }

    const int gc = c0 + tx * 4;
    const float4 bv = *(const float4*)(bias + gc);
    #pragma unroll
    for (int i = 0; i < 4; ++i) {
        const int gr = r0 + ty * 4 + i;
        if (gr < N_NODES) {
            float4 o;
            o.x = acc[i][0] + bv.x; o.y = acc[i][1] + bv.y;
            o.z = acc[i][2] + bv.z; o.w = acc[i][3] + bv.w;
            *(float4*)(y + (size_t)gr * D_OUT + gc) = o;
        }
    }
}

// ----------------------------------------------------------- CSR build ----
__global__ void init_csr(unsigned* __restrict__ deg, unsigned* __restrict__ total)
{
    const int i = blockIdx.x * 256 + threadIdx.x;
    if (i < N_NODES) deg[i] = 0u;
    if (i == 0) *total = 0u;
}

__global__ void hist_k(const int* __restrict__ ei, unsigned* __restrict__ deg)
{
    const int e = blockIdx.x * 256 + threadIdx.x;
    if (e < N_EDGES) atomicAdd(&deg[ei[N_EDGES + e]], 1u);
}

// per-wave shuffle scan of degrees; one global atomic per wave for the base
__global__ void row_start_k(const unsigned* __restrict__ deg,
                            unsigned* __restrict__ row_start,
                            unsigned* __restrict__ cursor,
                            unsigned* __restrict__ total)
{
    const int i    = blockIdx.x * 256 + threadIdx.x;
    const int lane = threadIdx.x & 63;
    const unsigned d = (i < N_NODES) ? deg[i] : 0u;

    // inclusive scan over the 64-lane wave
    unsigned v = d;
    #pragma unroll
    for (int off = 1; off < 64; off <<= 1) {
        unsigned t = __shfl_up(v, off, 64);
        if (lane >= off) v += t;
    }
    const unsigned excl = v - d;
    const unsigned wave_total = __shfl(v, 63, 64);

    unsigned base = 0;
    if (lane == 0) base = atomicAdd(total, wave_total);
    base = __shfl(base, 0, 64);

    if (i < N_NODES) {
        row_start[i] = base + excl;
        cursor[i]    = base + excl;
    }
}

__global__ void scatter_k(const int* __restrict__ ei,
                          unsigned* __restrict__ cursor,
                          int* __restrict__ csr_eid)
{
    const int e = blockIdx.x * 256 + threadIdx.x;
    if (e >= N_EDGES) return;
    const int dst = ei[N_EDGES + e];
    const unsigned pos = atomicAdd(&cursor[dst], 1u);
    csr_eid[pos] = e;
}

// -------------------------------------------------- edge pass: logits -----
// one 64-lane wave per edge; lane handles 4 of 256 dims
__global__ __launch_bounds__(256) void edge_logits(
    const float* __restrict__ xl, const float* __restrict__ xr,
    const int* __restrict__ ei, const float* __restrict__ att,
    float* __restrict__ e_buf)
{
    const int wave = (blockIdx.x * blockDim.x + threadIdx.x) >> 6;
    const int lane = threadIdx.x & 63;
    if (wave >= N_EDGES) return;
    const int src = ei[wave];
    const int dst = ei[N_EDGES + wave];

    const float4 a = *(const float4*)(att + lane * 4);
    const float4 l = *(const float4*)(xl + (size_t)src * D_OUT + lane * 4);
    const float4 r = *(const float4*)(xr + (size_t)dst * D_OUT + lane * 4);

    float h0 = l.x + r.x, h1 = l.y + r.y, h2 = l.z + r.z, h3 = l.w + r.w;
    h0 = h0 > 0.f ? h0 : NEG_SLOPE * h0;
    h1 = h1 > 0.f ? h1 : NEG_SLOPE * h1;
    h2 = h2 > 0.f ? h2 : NEG_SLOPE * h2;
    h3 = h3 > 0.f ? h3 : NEG_SLOPE * h3;
    float s = h0 * a.x + h1 * a.y + h2 * a.z + h3 * a.w;

    #pragma unroll
    for (int off = 32; off > 0; off >>= 1) s += __shfl_down(s, off, 64);

    if (lane == 0) e_buf[wave] = s;
}

// ------------------------------------ node aggregate: softmax + gather ----
// one 64-lane wave per dst node; lane owns 4 of 256 dims
__global__ __launch_bounds__(256) void node_agg(
    const float* __restrict__ xl, const int* __restrict__ ei,
    const float* __restrict__ e_buf, const int* __restrict__ csr_eid,
    const unsigned* __restrict__ row_start, const unsigned* __restrict__ deg,
    const float* __restrict__ bias, float* __restrict__ out)
{
    const int node = (blockIdx.x * blockDim.x + threadIdx.x) >> 6;
    const int lane = threadIdx.x & 63;
    if (node >= N_NODES) return;

    const int start = (int)row_start[node];
    const int cnt   = (int)deg[node];
    const int end   = start + cnt;

    // --- wave max over incoming-edge logits
    float m = -INFINITY;
    for (int j = start + lane; j < end; j += 64)
        m = fmaxf(m, e_buf[csr_eid[j]]);
    #pragma unroll
    for (int off = 32; off > 0; off >>= 1)
        m = fmaxf(m, __shfl_xor(m, off, 64));

    // --- wave sum of exp
    float s = 0.f;
    for (int j = start + lane; j < end; j += 64)
        s += __expf(e_buf[csr_eid[j]] - m);
    #pragma unroll
    for (int off = 32; off > 0; off >>= 1)
        s += __shfl_xor(s, off, 64);
    const float inv = 1.f / (s + 1e-16f);

    // --- weighted accumulate, lanes over dims
    float4 acc = make_float4(0.f, 0.f, 0.f, 0.f);
    for (int j = start; j < end; ++j) {
        const int eid = csr_eid[j];
        const int src = ei[eid];
        const float a = __expf(e_buf[eid] - m);
        const float4 l = *(const float4*)(xl + (size_t)src * D_OUT + lane * 4);
        acc.x += a * l.x; acc.y += a * l.y; acc.z += a * l.z; acc.w += a * l.w;
    }

    const float4 bv = *(const float4*)(bias + lane * 4);
    float4 o;
    o.x = acc.x * inv + bv.x; o.y = acc.y * inv + bv.y;
    o.z = acc.z * inv + bv.z; o.w = acc.w * inv + bv.w;
    *(float4*)(out + (size_t)node * D_OUT + lane * 4) = o;
}

// --------------------------------------------------------------- launch ---
extern "C" void kernel_launch(void* const* d_in, const int* in_sizes, int n_in,
                              void* d_out, int out_size, void* d_ws, size_t ws_size,
                              hipStream_t stream)
{
    const float* x   = (const float*)d_in[0];
    const int*   ei  = (const int*)  d_in[1];
    const float* W_l = (const float*)d_in[2];
    const float* b_l = (const float*)d_in[3];
    const float* W_r = (const float*)d_in[4];
    const float* b_r = (const float*)d_in[5];
    const float* att = (const float*)d_in[6];
    const float* bias= (const float*)d_in[7];
    float* out = (float*)d_out;

    // workspace layout (4-byte elements)
    float*    xl        = (float*)d_ws;                     // N*256
    float*    xr        = xl + (size_t)N_NODES * D_OUT;     // N*256
    float*    e_buf     = xr + (size_t)N_NODES * D_OUT;     // E
    int*      csr_eid   = (int*)(e_buf + N_EDGES);          // E
    unsigned* deg       = (unsigned*)(csr_eid + N_EDGES);   // N
    unsigned* row_start = deg + N_NODES;                    // N
    unsigned* cursor    = row_start + N_NODES;              // N
    unsigned* total     = cursor + N_NODES;                 // 1

    // 1) x_l / x_r dual GEMM
    dim3 ggrid((N_NODES + BM - 1) / BM, D_OUT / BN, 2);
    gemm_xw<<<ggrid, 256, 0, stream>>>(x, W_l, b_l, xl, W_r, b_r, xr);

    // 2) CSR build (independent of GEMM)
    const int nb_nodes = (N_NODES + 255) / 256;
    const int nb_edges = (N_EDGES + 255) / 256;
    init_csr<<<nb_nodes, 256, 0, stream>>>(deg, total);
    hist_k<<<nb_edges, 256, 0, stream>>>(ei, deg);
    row_start_k<<<nb_nodes, 256, 0, stream>>>(deg, row_start, cursor, total);
    scatter_k<<<nb_edges, 256, 0, stream>>>(ei, cursor, csr_eid);

    // 3) per-edge attention logits
    edge_logits<<<N_EDGES / 4, 256, 0, stream>>>(xl, xr, ei, att, e_buf);

    // 4) per-node softmax + weighted aggregate
    node_agg<<<(N_NODES * 64 + 255) / 256, 256, 0, stream>>>(
        xl, ei, e_buf, csr_eid, row_start, deg, bias, out);
}

// Round 3
// 1375.115 us; speedup vs baseline: 4.9165x; 1.3600x over previous
//
#include <hip/hip_runtime.h>
#include <hip/hip_bf16.h>

#define N_NODES 100000
#define N_EDGES 1600000
#define D_IN    480
#define D_OUT   256
#define NEG_SLOPE 0.2f

// ---------------------------------------------------------------- GEMM ----
// y[n, 256] = x[n, 480] @ W[480, 256] + b ; blockIdx.z selects (W_l) vs (W_r)
#define BM 64
#define BN 64
#define BK 32

__global__ __launch_bounds__(256) void gemm_xw(
    const float* __restrict__ x,
    const float* __restrict__ Wl, const float* __restrict__ bl, float* __restrict__ yl,
    const float* __restrict__ Wr, const float* __restrict__ br, float* __restrict__ yr)
{
    const float* W = (blockIdx.z == 0) ? Wl : Wr;
    const float* bias = (blockIdx.z == 0) ? bl : br;
    float* y = (blockIdx.z == 0) ? yl : yr;

    __shared__ float As[BK][BM + 1];
    __shared__ float Bs[BK][BN];

    const int r0 = blockIdx.x * BM;
    const int c0 = blockIdx.y * BN;
    const int t  = threadIdx.x;
    const int ty = t >> 4;
    const int tx = t & 15;

    float acc[4][4] = {};

    for (int k0 = 0; k0 < D_IN; k0 += BK) {
        {
            const int row = t >> 3;
            const int kk  = (t & 7) * 4;
            #pragma unroll
            for (int rr = row; rr < BM; rr += 32) {
                const int gr = r0 + rr;
                float4 v = make_float4(0.f, 0.f, 0.f, 0.f);
                if (gr < N_NODES)
                    v = *(const float4*)(x + (size_t)gr * D_IN + k0 + kk);
                As[kk + 0][rr] = v.x; As[kk + 1][rr] = v.y;
                As[kk + 2][rr] = v.z; As[kk + 3][rr] = v.w;
            }
        }
        {
            const int kk  = t >> 4;
            const int col = (t & 15) * 4;
            *(float4*)&Bs[kk][col] =
                *(const float4*)(W + (size_t)(k0 + kk) * D_OUT + c0 + col);
            *(float4*)&Bs[kk + 16][col] =
                *(const float4*)(W + (size_t)(k0 + kk + 16) * D_OUT + c0 + col);
        }
        __syncthreads();

        #pragma unroll
        for (int kk = 0; kk < BK; ++kk) {
            float a0 = As[kk][ty * 4 + 0];
            float a1 = As[kk][ty * 4 + 1];
            float a2 = As[kk][ty * 4 + 2];
            float a3 = As[kk][ty * 4 + 3];
            float b0 = Bs[kk][tx * 4 + 0];
            float b1 = Bs[kk][tx * 4 + 1];
            float b2 = Bs[kk][tx * 4 + 2];
            float b3 = Bs[kk][tx * 4 + 3];
            acc[0][0] += a0 * b0; acc[0][1] += a0 * b1; acc[0][2] += a0 * b2; acc[0][3] += a0 * b3;
            acc[1][0] += a1 * b0; acc[1][1] += a1 * b1; acc[1][2] += a1 * b2; acc[1][3] += a1 * b3;
            acc[2][0] += a2 * b0; acc[2][1] += a2 * b1; acc[2][2] += a2 * b2; acc[2][3] += a2 * b3;
            acc[3][0] += a3 * b0; acc[3][1] += a3 * b1; acc[3][2] += a3 * b2; acc[3][3] += a3 * b3;
        }
        __syncthreads();
    }

    const int gc = c0 + tx * 4;
    const float4 bv = *(const float4*)(bias + gc);
    #pragma unroll
    for (int i = 0; i < 4; ++i) {
        const int gr = r0 + ty * 4 + i;
        if (gr < N_NODES) {
            float4 o;
            o.x = acc[i][0] + bv.x; o.y = acc[i][1] + bv.y;
            o.z = acc[i][2] + bv.z; o.w = acc[i][3] + bv.w;
            *(float4*)(y + (size_t)gr * D_OUT + gc) = o;
        }
    }
}

// ----------------------------------------------------------- CSR build ----
__global__ void init_csr(unsigned* __restrict__ deg, unsigned* __restrict__ total)
{
    const int i = blockIdx.x * 256 + threadIdx.x;
    if (i < N_NODES) deg[i] = 0u;
    if (i == 0) *total = 0u;
}

__global__ void hist_k(const int* __restrict__ ei, unsigned* __restrict__ deg)
{
    const int e = blockIdx.x * 256 + threadIdx.x;
    if (e < N_EDGES) atomicAdd(&deg[ei[N_EDGES + e]], 1u);
}

// per-wave shuffle scan of degrees; one global atomic per wave for the base
__global__ void row_start_k(const unsigned* __restrict__ deg,
                            unsigned* __restrict__ row_start,
                            unsigned* __restrict__ cursor,
                            unsigned* __restrict__ total)
{
    const int i    = blockIdx.x * 256 + threadIdx.x;
    const int lane = threadIdx.x & 63;
    const unsigned d = (i < N_NODES) ? deg[i] : 0u;

    unsigned v = d;
    #pragma unroll
    for (int off = 1; off < 64; off <<= 1) {
        unsigned t = __shfl_up(v, off, 64);
        if (lane >= off) v += t;
    }
    const unsigned excl = v - d;
    const unsigned wave_total = __shfl(v, 63, 64);

    unsigned base = 0;
    if (lane == 0) base = atomicAdd(total, wave_total);
    base = __shfl(base, 0, 64);

    if (i < N_NODES) {
        row_start[i] = base + excl;
        cursor[i]    = base + excl;
    }
}

__global__ void scatter_k(const int* __restrict__ ei,
                          unsigned* __restrict__ cursor,
                          int* __restrict__ csr_src)
{
    const int e = blockIdx.x * 256 + threadIdx.x;
    if (e >= N_EDGES) return;
    const int dst = ei[N_EDGES + e];
    const unsigned pos = atomicAdd(&cursor[dst], 1u);
    csr_src[pos] = ei[e];   // store SOURCE node id directly (skip eid indirection)
}

// ---------------- fused node aggregate: logits + online softmax + gather --
// one 64-lane wave per dst node; lane owns 4 of 256 dims
__global__ __launch_bounds__(256) void node_agg(
    const float* __restrict__ xl, const float* __restrict__ xr,
    const float* __restrict__ att, const int* __restrict__ csr_src,
    const unsigned* __restrict__ row_start, const unsigned* __restrict__ deg,
    const float* __restrict__ bias, float* __restrict__ out)
{
    const int node = (blockIdx.x * blockDim.x + threadIdx.x) >> 6;
    const int lane = threadIdx.x & 63;
    if (node >= N_NODES) return;

    const int start = (int)row_start[node];
    const int cnt   = (int)deg[node];
    const int end   = start + cnt;

    const float4 a  = *(const float4*)(att + lane * 4);
    const float4 r  = *(const float4*)(xr + (size_t)node * D_OUT + lane * 4);

    float  m = -INFINITY;               // running max
    float  s = 0.f;                     // running denom
    float4 acc = make_float4(0.f, 0.f, 0.f, 0.f);

    // software-pipelined: prefetch next edge's xl gather ahead of the shuffle chain
    float4 l = make_float4(0.f, 0.f, 0.f, 0.f);
    if (start < end)
        l = *(const float4*)(xl + (size_t)csr_src[start] * D_OUT + lane * 4);

    for (int j = start; j < end; ++j) {
        float4 l_next = make_float4(0.f, 0.f, 0.f, 0.f);
        if (j + 1 < end)
            l_next = *(const float4*)(xl + (size_t)csr_src[j + 1] * D_OUT + lane * 4);

        // e = att . leakyReLU(l + r), wave-reduced
        float h0 = l.x + r.x, h1 = l.y + r.y, h2 = l.z + r.z, h3 = l.w + r.w;
        h0 = h0 > 0.f ? h0 : NEG_SLOPE * h0;
        h1 = h1 > 0.f ? h1 : NEG_SLOPE * h1;
        h2 = h2 > 0.f ? h2 : NEG_SLOPE * h2;
        h3 = h3 > 0.f ? h3 : NEG_SLOPE * h3;
        float e = h0 * a.x + h1 * a.y + h2 * a.z + h3 * a.w;
        #pragma unroll
        for (int off = 32; off > 0; off >>= 1)
            e += __shfl_xor(e, off, 64);

        // online softmax update
        const float m_new = fmaxf(m, e);
        const float scale = __expf(m - m_new);   // 0 when m was -inf
        const float p     = __expf(e - m_new);
        s = s * scale + p;
        acc.x = acc.x * scale + p * l.x;
        acc.y = acc.y * scale + p * l.y;
        acc.z = acc.z * scale + p * l.z;
        acc.w = acc.w * scale + p * l.w;
        m = m_new;

        l = l_next;
    }

    const float inv = 1.f / (s + 1e-16f);
    const float4 bv = *(const float4*)(bias + lane * 4);
    float4 o;
    o.x = acc.x * inv + bv.x; o.y = acc.y * inv + bv.y;
    o.z = acc.z * inv + bv.z; o.w = acc.w * inv + bv.w;
    *(float4*)(out + (size_t)node * D_OUT + lane * 4) = o;
}

// --------------------------------------------------------------- launch ---
extern "C" void kernel_launch(void* const* d_in, const int* in_sizes, int n_in,
                              void* d_out, int out_size, void* d_ws, size_t ws_size,
                              hipStream_t stream)
{
    const float* x   = (const float*)d_in[0];
    const int*   ei  = (const int*)  d_in[1];
    const float* W_l = (const float*)d_in[2];
    const float* b_l = (const float*)d_in[3];
    const float* W_r = (const float*)d_in[4];
    const float* b_r = (const float*)d_in[5];
    const float* att = (const float*)d_in[6];
    const float* bias= (const float*)d_in[7];
    float* out = (float*)d_out;

    // workspace layout (4-byte elements)
    float*    xl        = (float*)d_ws;                     // N*256
    float*    xr        = xl + (size_t)N_NODES * D_OUT;     // N*256
    int*      csr_src   = (int*)(xr + (size_t)N_NODES * D_OUT); // E
    unsigned* deg       = (unsigned*)(csr_src + N_EDGES);   // N
    unsigned* row_start = deg + N_NODES;                    // N
    unsigned* cursor    = row_start + N_NODES;              // N
    unsigned* total     = cursor + N_NODES;                 // 1

    // 1) x_l / x_r dual GEMM
    dim3 ggrid((N_NODES + BM - 1) / BM, D_OUT / BN, 2);
    gemm_xw<<<ggrid, 256, 0, stream>>>(x, W_l, b_l, xl, W_r, b_r, xr);

    // 2) CSR build (independent of GEMM)
    const int nb_nodes = (N_NODES + 255) / 256;
    const int nb_edges = (N_EDGES + 255) / 256;
    init_csr<<<nb_nodes, 256, 0, stream>>>(deg, total);
    hist_k<<<nb_edges, 256, 0, stream>>>(ei, deg);
    row_start_k<<<nb_nodes, 256, 0, stream>>>(deg, row_start, cursor, total);
    scatter_k<<<nb_edges, 256, 0, stream>>>(ei, cursor, csr_src);

    // 3) fused logits + softmax + aggregate (one wave per node)
    node_agg<<<(N_NODES + 3) / 4, 256, 0, stream>>>(
        xl, xr, att, csr_src, row_start, deg, bias, out);
}